// Round 11
// baseline (1118.435 us; speedup 1.0000x reference)
//
#include <hip/hip_runtime.h>
#include <stdint.h>

typedef _Float16 half8 __attribute__((ext_vector_type(8)));
typedef float f32x4 __attribute__((ext_vector_type(4)));

#define DDIM 256
#define KCODES 4096
#define BM 64
#define DELTA 0.02f
#define FLT_BIG 3.4e38f

#define GLOAD_LDS(gsrc, ldst)                                                        \
    __builtin_amdgcn_global_load_lds(                                                \
        (const __attribute__((address_space(1))) void*)(const void*)(gsrc),          \
        (__attribute__((address_space(3))) void*)(void*)(ldst), 16, 0, 0)

// ---------- codebook -> fragment-ordered hi/lo fp16 ----------
// cbp[g*1024 + k*128 + part*64 + l] (half8 units), lane l: code g*16+(l&15),
// dims k*32 + ((l>>4)&3)*8 .. +7   (part 0 = hi, 1 = lo)
__global__ void cvt_cb_kernel(const float* __restrict__ cb, half8* __restrict__ cbp) {
    int gid = blockIdx.x * 256 + threadIdx.x;    // 131072
    int l = gid & 63;
    int k = (gid >> 6) & 7;
    int g = gid >> 9;
    int code = g * 16 + (l & 15);
    int quad = (l >> 4) & 3;
    const float* s = cb + (size_t)code * DDIM + k * 32 + quad * 8;
    float4 f0 = ((const float4*)s)[0];
    float4 f1 = ((const float4*)s)[1];
    float ff[8] = {f0.x, f0.y, f0.z, f0.w, f1.x, f1.y, f1.z, f1.w};
    half8 hv, lv;
    #pragma unroll
    for (int j = 0; j < 8; ++j) {
        float v = ff[j];
        _Float16 h = (_Float16)v;
        hv[j] = h; lv[j] = (_Float16)(v - (float)h);
    }
    cbp[(size_t)(g * 8 + k) * 128 + l] = hv;
    cbp[(size_t)(g * 8 + k) * 128 + 64 + l] = lv;
}

__global__ void enorm_kernel(const float* __restrict__ cb, float* __restrict__ en, int K) {
    int gid = blockIdx.x * blockDim.x + threadIdx.x;
    int code = gid >> 6;
    int lane = threadIdx.x & 63;
    if (code >= K) return;
    const float4 v = *reinterpret_cast<const float4*>(&cb[(size_t)code * DDIM + lane * 4]);
    float s = v.x * v.x + v.y * v.y + v.z * v.z + v.w * v.w;
    #pragma unroll
    for (int off = 32; off > 0; off >>= 1) s += __shfl_xor(s, off, 64);
    if (lane == 0) en[code] = s;
}

// ---------------- main: A-stationary-in-registers, barrier-free K-loop ----------------
__global__ __launch_bounds__(512, 2)
void vq_mfma_kernel(const float* __restrict__ x, const half8* __restrict__ cbp,
                    const float* __restrict__ en, const float* __restrict__ cb,
                    float* out, int* __restrict__ list, int* __restrict__ counter,
                    float* __restrict__ loss_accum, int N) {
    __shared__ __align__(16) float xs[BM * DDIM];     // 64 KB staged x (chunk-swizzled)
    __shared__ float en_lds[KCODES];                  // 16 KB
    __shared__ float red_d[8][BM];
    __shared__ float red_d2[8][BM];
    __shared__ int   red_i[8][BM];
    __shared__ int   binfo[BM];
    __shared__ float wsum[8];

    const int tid = threadIdx.x;
    const int lane = tid & 63;
    const int w = tid >> 6;
    const int l15 = lane & 15, l4 = lane >> 4;
    const int brow = blockIdx.x * BM;
    const size_t ND = (size_t)N * DDIM;

    ((float4*)en_lds)[tid] = ((const float4*)en)[tid];
    ((float4*)en_lds)[tid + 512] = ((const float4*)en)[tid + 512];

    // ---- stage x rows (fp32) into LDS, chunk-XOR swizzled, coalesced ----
    // wave w, instr i stages row i*8+w; LDS[row][c] = x[row][chunk c ^ (row&7)]
    #pragma unroll
    for (int i = 0; i < 8; ++i) {
        const int row = i * 8 + w;                    // row & 7 == w (wave-uniform)
        const float* src = x + (size_t)(brow + row) * DDIM + ((lane ^ w) << 2);
        GLOAD_LDS(src, xs + row * DDIM + (lane << 2));
    }
    __syncthreads();    // drains gload_lds + en_lds writes

    // ---- A fragments to registers: 64 rows x 256 dims hi/lo = 128 VGPR ----
    half8 ahf[4][8], alf[4][8];
    const int s7 = l15 & 7;
    #pragma unroll
    for (int n = 0; n < 4; ++n) {
        const float* base = xs + (n * 16 + l15) * DDIM;
        #pragma unroll
        for (int k = 0; k < 8; ++k) {
            int c0 = (k * 8 + l4 * 2) ^ s7;
            float4 f0 = *(const float4*)(base + c0 * 4);
            float4 f1 = *(const float4*)(base + (c0 ^ 1) * 4);
            float ff[8] = {f0.x, f0.y, f0.z, f0.w, f1.x, f1.y, f1.z, f1.w};
            half8 hv, lv;
            #pragma unroll
            for (int j = 0; j < 8; ++j) {
                float v = ff[j];
                _Float16 h = (_Float16)v;
                hv[j] = h; lv[j] = (_Float16)(v - (float)h);
            }
            ahf[n][k] = hv; alf[n][k] = lv;
        }
    }

    // ---- barrier-free main loop: wave w owns codes [w*512, (w+1)*512) ----
    float bestv[4], best2v[4];
    int bidv[4];
    #pragma unroll
    for (int i = 0; i < 4; ++i) { bestv[i] = FLT_BIG; best2v[i] = FLT_BIG; bidv[i] = 0; }

#define TRI(accr, bh_, bl_, ah_, al_) do {                                              \
        accr = __builtin_amdgcn_mfma_f32_16x16x32_f16(bh_, ah_, accr, 0, 0, 0);         \
        accr = __builtin_amdgcn_mfma_f32_16x16x32_f16(bl_, ah_, accr, 0, 0, 0);         \
        accr = __builtin_amdgcn_mfma_f32_16x16x32_f16(bh_, al_, accr, 0, 0, 0);         \
    } while (0)

    const half8* pb = cbp + (size_t)w * 32768 + lane;   // 32 groups x 1024 half8
    int gbase = w * 512;

    for (int gi = 0; gi < 32; ++gi) {
        // prefetch all 16 B-fragments of this group (coalesced 1KB wave-loads, L2-hit)
        half8 bh[8], bl[8];
        #pragma unroll
        for (int k = 0; k < 8; ++k) {
            bh[k] = pb[k * 128];
            bl[k] = pb[k * 128 + 64];
        }
        f32x4 acc[4];
        #pragma unroll
        for (int n = 0; n < 4; ++n) acc[n] = (f32x4){0.f, 0.f, 0.f, 0.f};
        #pragma unroll
        for (int k = 0; k < 8; ++k) {
            #pragma unroll
            for (int n = 0; n < 4; ++n)
                TRI(acc[n], bh[k], bl[k], ahf[n][k], alf[n][k]);
        }
        // epilogue: dist = ||e||^2 - 2*dot ; code = gbase + l4*4 + r, row = n*16+l15
        float4 e4 = *(const float4*)(en_lds + gbase + l4 * 4);
        #pragma unroll
        for (int r = 0; r < 4; ++r) {
            int code = gbase + l4 * 4 + r;
            float e = (r == 0) ? e4.x : (r == 1) ? e4.y : (r == 2) ? e4.z : e4.w;
            #pragma unroll
            for (int n = 0; n < 4; ++n) {
                float dist = fmaf(-2.f, acc[n][r], e);
                if (dist < bestv[n]) { best2v[n] = bestv[n]; bestv[n] = dist; bidv[n] = code; }
                else if (dist < best2v[n]) best2v[n] = dist;
            }
        }
        pb += 1024;
        gbase += 16;
    }
#undef TRI

    // ---- cross-lane merge (over l4): candidates for row n*16+l15 ----
    #pragma unroll
    for (int n = 0; n < 4; ++n) {
        float d = bestv[n], d2 = best2v[n];
        int ix = bidv[n];
        #pragma unroll
        for (int off = 16; off < 64; off <<= 1) {
            float od = __shfl_xor(d, off, 64);
            float od2 = __shfl_xor(d2, off, 64);
            int oi = __shfl_xor(ix, off, 64);
            if (od < d || (od == d && oi < ix)) { d2 = fminf(d, od2); d = od; ix = oi; }
            else d2 = fminf(d2, od);
        }
        if (l4 == 0) {
            int row = n * 16 + l15;
            red_d[w][row] = d;
            red_d2[w][row] = d2;
            red_i[w][row] = ix;
        }
    }
    __syncthreads();

    // ---- cross-wave merge + index write + flag append ----
    if (tid < BM) {
        float d = red_d[0][tid], d2 = red_d2[0][tid];
        int ix = red_i[0][tid];
        #pragma unroll
        for (int q = 1; q < 8; ++q) {
            float od = red_d[q][tid], od2 = red_d2[q][tid];
            int oi = red_i[q][tid];
            if (od < d || (od == d && oi < ix)) { d2 = fminf(d, od2); d = od; ix = oi; }
            else d2 = fminf(d2, od);
        }
        int fl = (d2 - d < DELTA) ? 1 : 0;
        out[ND + 1 + brow + tid] = (float)ix;
        binfo[tid] = ix | (fl << 16);
        if (fl) {
            int pos = atomicAdd(counter, 1);
            list[pos] = brow + tid;
        }
    }
    __syncthreads();

    // ---- fused gather + loss (flagged rows: provisional write, no loss) ----
    float lsum = 0.f;
    #pragma unroll
    for (int pp = 0; pp < 8; ++pp) {
        int i = tid + pp * 512;       // 0..4095 float4-units
        int row = i >> 6;
        int c4 = (i & 63) << 2;
        int info = binfo[row];
        int code = info & 0xffff;
        const float4 q = *reinterpret_cast<const float4*>(&cb[(size_t)code * DDIM + c4]);
        const float4 xv = *reinterpret_cast<const float4*>(&x[(size_t)(brow + row) * DDIM + c4]);
        float d0 = xv.x - q.x, d1 = xv.y - q.y, d2 = xv.z - q.z, d3 = xv.w - q.w;
        if (!(info >> 16)) lsum += d0 * d0 + d1 * d1 + d2 * d2 + d3 * d3;
        *reinterpret_cast<float4*>(&out[(size_t)(brow + row) * DDIM + c4]) = q;
    }
    #pragma unroll
    for (int off = 32; off > 0; off >>= 1) lsum += __shfl_xor(lsum, off, 64);
    if (lane == 0) wsum[w] = lsum;
    __syncthreads();
    if (tid == 0) {
        float tot = 0.f;
        #pragma unroll
        for (int q = 0; q < 8; ++q) tot += wsum[q];
        atomicAdd(loss_accum, tot * (0.25f / (float)ND));
    }
}

// ---------------- exact fp32 rescan: repairs flagged rows completely ----------------
__global__ __launch_bounds__(256)
void rescan_kernel(const float* __restrict__ x, const float* __restrict__ cb,
                   const float* __restrict__ en, const int* __restrict__ list,
                   const int* __restrict__ counter, float* out,
                   float* __restrict__ loss_accum, int N) {
    __shared__ __align__(16) float4 xrow4[64];
    __shared__ float wd[4];
    __shared__ int wi[4];
    __shared__ float wls[4];
    __shared__ int six;
    const int tid = threadIdx.x;
    const int w = tid >> 6;
    const int lane = tid & 63;
    const int cnt = *counter;
    const size_t ND = (size_t)N * DDIM;

    for (int it = blockIdx.x; it < cnt; it += gridDim.x) {
        const int row = list[it];
        __syncthreads();
        if (tid < 64) xrow4[tid] = ((const float4*)&x[(size_t)row * DDIM])[tid];
        __syncthreads();
        const float4 xv = xrow4[lane];
        float bd = FLT_BIG;
        int bi = 0;
        for (int i = 0; i < KCODES / 4; ++i) {
            int code = i * 4 + w;
            const float4 c4 = ((const float4*)&cb[(size_t)code * DDIM])[lane];
            float s = xv.x * c4.x + xv.y * c4.y + xv.z * c4.z + xv.w * c4.w;
            #pragma unroll
            for (int off = 1; off < 64; off <<= 1) s += __shfl_xor(s, off, 64);
            float dist = fmaf(-2.f, s, en[code]);
            if (dist < bd) { bd = dist; bi = code; }
        }
        if (lane == 0) { wd[w] = bd; wi[w] = bi; }
        __syncthreads();
        if (tid == 0) {
            float d = wd[0]; int ix = wi[0];
            #pragma unroll
            for (int q = 1; q < 4; ++q) {
                if (wd[q] < d || (wd[q] == d && wi[q] < ix)) { d = wd[q]; ix = wi[q]; }
            }
            six = ix;
            out[ND + 1 + row] = (float)ix;
        }
        __syncthreads();
        const int ix = six;
        float c = cb[(size_t)ix * DDIM + tid];
        float xs_ = ((const float*)xrow4)[tid];
        out[(size_t)row * DDIM + tid] = c;
        float dd = xs_ - c;
        float ss = dd * dd;
        #pragma unroll
        for (int off = 32; off > 0; off >>= 1) ss += __shfl_xor(ss, off, 64);
        if (lane == 0) wls[w] = ss;
        __syncthreads();
        if (tid == 0) {
            float tot = wls[0] + wls[1] + wls[2] + wls[3];
            atomicAdd(loss_accum, tot * (0.25f / (float)ND));
        }
    }
}

__global__ void loss_fin_kernel(const float* __restrict__ loss_accum,
                                float* __restrict__ out, size_t off) {
    if (blockIdx.x == 0 && threadIdx.x == 0) out[off] = *loss_accum;
}

extern "C" void kernel_launch(void* const* d_in, const int* in_sizes, int n_in,
                              void* d_out, int out_size, void* d_ws, size_t ws_size,
                              hipStream_t stream) {
    const float* x = (const float*)d_in[0];
    const float* cb = (const float*)d_in[1];
    const int N = in_sizes[0] / DDIM;    // 65536
    const int K = in_sizes[1] / DDIM;    // 4096
    float* out = (float*)d_out;

    half8* cbp = (half8*)d_ws;           // 4 MB fragment-ordered codebook
    char* p = (char*)d_ws + (4 << 20);
    float* en = (float*)p;                  p += (size_t)K * 4;
    int* list = (int*)p;                    p += (size_t)N * 4;
    int* counter = (int*)p;                 p += 64;
    float* loss_accum = (float*)p;

    hipMemsetAsync(counter, 0, sizeof(int), stream);
    hipMemsetAsync(loss_accum, 0, sizeof(float), stream);
    cvt_cb_kernel<<<(K * 32) / 256, 256, 0, stream>>>(cb, cbp);
    enorm_kernel<<<(K * 64) / 256, 256, 0, stream>>>(cb, en, K);
    vq_mfma_kernel<<<N / BM, 512, 0, stream>>>(x, cbp, en, cb, out,
                                               list, counter, loss_accum, N);
    rescan_kernel<<<512, 256, 0, stream>>>(x, cb, en, list, counter, out, loss_accum, N);
    loss_fin_kernel<<<1, 64, 0, stream>>>(loss_accum, out, (size_t)N * DDIM);
}